// Round 1
// baseline (197.106 us; speedup 1.0000x reference)
//
#include <hip/hip_runtime.h>

#define B 8
#define L 512
#define D 256
#define U 32

// ---------------------------------------------------------------------------
// Kernel 1: qb[b,l,u] = sum_d x[b,l,d]*Wt[d,u] + bh[u]
//           kk[b,l,u] = sum_d x[b,l,d]*Wx[d,u]
// Grid: B*L blocks, 64 threads (lanes 0-31 -> q, 32-63 -> k)
// ---------------------------------------------------------------------------
__global__ __launch_bounds__(64) void qk_kernel(
    const float* __restrict__ x,
    const float* __restrict__ Wt,
    const float* __restrict__ Wx,
    const float* __restrict__ bh,
    float* __restrict__ qb,
    float* __restrict__ kk)
{
    const int row = blockIdx.x;                 // b*L + l
    const int u   = threadIdx.x & 31;
    const bool isK = threadIdx.x >= 32;
    const float* __restrict__ W = isK ? Wx : Wt;
    const float* __restrict__ xr = x + row * D;

    float acc = 0.f;
    #pragma unroll 8
    for (int d = 0; d < D; ++d)
        acc = fmaf(xr[d], W[d * U + u], acc);

    if (isK) kk[row * U + u] = acc;
    else     qb[row * U + u] = acc + bh[u];
}

// fast tanh: exact saturation at +/-inf, ~ulp-accurate via v_exp_f32
__device__ __forceinline__ float tanh_fast(float z) {
    float e = __expf(2.f * z);
    return 1.f - 2.f / (e + 1.f);
}

// ---------------------------------------------------------------------------
// Kernel 2: one block per (b,s). 256 threads.
//  A) alpha[t] = sum_u tanh(qb[s,u]+kk[t,u])*Wa[u] + ba    (t = tid, tid+256)
//  B) softmax over t (block reduction)
//  C) out[d] = sum_t a[t]*x[b,t,d]                          (d = tid)
// ---------------------------------------------------------------------------
__global__ __launch_bounds__(256) void attn_kernel(
    const float* __restrict__ x,
    const float* __restrict__ qb,
    const float* __restrict__ kk,
    const float* __restrict__ Wa,
    const float* __restrict__ ba,
    float* __restrict__ out)
{
    const int bs  = blockIdx.x;      // b*L + s
    const int b   = bs >> 9;         // / L
    const int tid = threadIdx.x;

    __shared__ float qs[U];
    __shared__ float wa[U];
    __shared__ float a_sh[L];
    __shared__ float red[8];         // [0..3] max, [4..7] sum (4 waves)

    if (tid < U) {
        qs[tid] = qb[bs * U + tid];
        wa[tid] = Wa[tid];
    }
    __syncthreads();

    const float  ba0 = ba[0];
    const float* __restrict__ kb = kk + b * L * U;

    float av[2];
    #pragma unroll
    for (int i = 0; i < 2; ++i) {
        const int t = tid + i * 256;
        const float* __restrict__ kr = kb + t * U;
        float acc = 0.f;
        #pragma unroll
        for (int u = 0; u < U; ++u)
            acc = fmaf(tanh_fast(qs[u] + kr[u]), wa[u], acc);
        av[i] = acc + ba0;
    }

    // ---- block max ----
    float m = fmaxf(av[0], av[1]);
    #pragma unroll
    for (int off = 1; off < 64; off <<= 1)
        m = fmaxf(m, __shfl_xor(m, off));
    const int wave = tid >> 6;
    if ((tid & 63) == 0) red[wave] = m;
    __syncthreads();
    m = fmaxf(fmaxf(red[0], red[1]), fmaxf(red[2], red[3]));

    // ---- exp + block sum ----
    float e0 = __expf(av[0] - m);
    float e1 = __expf(av[1] - m);
    float s = e0 + e1;
    #pragma unroll
    for (int off = 1; off < 64; off <<= 1)
        s += __shfl_xor(s, off);
    if ((tid & 63) == 0) red[4 + wave] = s;
    __syncthreads();
    s = (red[4] + red[5]) + (red[6] + red[7]);
    const float inv = 1.f / s;

    a_sh[tid]       = e0 * inv;
    a_sh[tid + 256] = e1 * inv;
    __syncthreads();

    // ---- weighted sum over keys: out[bs, tid] ----
    const float* __restrict__ xb = x + b * L * D;
    float acc = 0.f;
    #pragma unroll 8
    for (int t = 0; t < L; ++t)
        acc = fmaf(a_sh[t], xb[t * D + tid], acc);
    out[bs * D + tid] = acc;
}

extern "C" void kernel_launch(void* const* d_in, const int* in_sizes, int n_in,
                              void* d_out, int out_size, void* d_ws, size_t ws_size,
                              hipStream_t stream)
{
    const float* x  = (const float*)d_in[0];
    const float* Wt = (const float*)d_in[1];
    const float* Wx = (const float*)d_in[2];
    const float* bh = (const float*)d_in[3];
    const float* Wa = (const float*)d_in[4];
    const float* ba = (const float*)d_in[5];
    float* out = (float*)d_out;

    float* qb = (float*)d_ws;                    // B*L*U floats
    float* kk = qb + B * L * U;                  // B*L*U floats

    qk_kernel<<<B * L, 64, 0, stream>>>(x, Wt, Wx, bh, qb, kk);
    attn_kernel<<<B * L, 256, 0, stream>>>(x, qb, kk, Wa, ba, out);
}

// Round 2
// 121.645 us; speedup vs baseline: 1.6203x; 1.6203x over previous
//
#include <hip/hip_runtime.h>

#define B 8
#define L 512
#define D 256
#define U 32
#define ST 8          // queries (s) per attn block
#define TR 32         // rows per qk block

// tanh(z) = 1 - 2/(exp(2z)+1), exp via hw exp2: 2*log2(e) = 2.885390082
__device__ __forceinline__ float tanh_fast(float z) {
    float e = __builtin_amdgcn_exp2f(z * 2.885390081777927f);
    return 1.f - 2.f * __builtin_amdgcn_rcpf(e + 1.f);
}

// ---------------------------------------------------------------------------
// qk: qb[row,u] = sum_d x[row,d]*Wt[d,u] + bh[u];  kk[row,u] = sum_d x*Wx
// grid = B*L/TR = 128 blocks, 256 threads = 32 rows x 8 u-groups(float4)
// ---------------------------------------------------------------------------
__global__ __launch_bounds__(256) void qk_kernel(
    const float* __restrict__ x,
    const float* __restrict__ Wt,
    const float* __restrict__ Wx,
    const float* __restrict__ bh,
    float* __restrict__ qb,
    float* __restrict__ kk)
{
    __shared__ float xs[TR][D + 1];          // +1 pad: banks (r+d)%32
    const int row0 = blockIdx.x * TR;
    const int tid  = threadIdx.x;

    // stage x tile (TR*D floats) via float4
    const float4* xg = (const float4*)(x + row0 * D);
    for (int i = tid; i < TR * D / 4; i += 256) {
        float4 v = xg[i];
        int r = i >> 6;              // / (D/4)
        int c = (i & 63) << 2;
        xs[r][c] = v.x; xs[r][c + 1] = v.y; xs[r][c + 2] = v.z; xs[r][c + 3] = v.w;
    }
    __syncthreads();

    const int r = tid >> 3;          // 0..31
    const int g = tid & 7;           // u = 4g..4g+3
    const float4* __restrict__ Wt4 = (const float4*)Wt;
    const float4* __restrict__ Wx4 = (const float4*)Wx;

    float4 qa = {0.f, 0.f, 0.f, 0.f};
    float4 ka = {0.f, 0.f, 0.f, 0.f};
    #pragma unroll 4
    for (int d = 0; d < D; ++d) {
        float  xv = xs[r][d];
        float4 wt = Wt4[d * 8 + g];
        float4 wx = Wx4[d * 8 + g];
        qa.x = fmaf(xv, wt.x, qa.x); qa.y = fmaf(xv, wt.y, qa.y);
        qa.z = fmaf(xv, wt.z, qa.z); qa.w = fmaf(xv, wt.w, qa.w);
        ka.x = fmaf(xv, wx.x, ka.x); ka.y = fmaf(xv, wx.y, ka.y);
        ka.z = fmaf(xv, wx.z, ka.z); ka.w = fmaf(xv, wx.w, ka.w);
    }
    float4 b4 = ((const float4*)bh)[g];
    qa.x += b4.x; qa.y += b4.y; qa.z += b4.z; qa.w += b4.w;

    const int row = row0 + r;
    ((float4*)qb)[row * 8 + g] = qa;
    ((float4*)kk)[row * 8 + g] = ka;
}

// ---------------------------------------------------------------------------
// attn: one block per (b, s-tile of 8). 256 threads, 4 waves.
// ---------------------------------------------------------------------------
__global__ __launch_bounds__(256) void attn_kernel(
    const float* __restrict__ x,
    const float* __restrict__ qb,
    const float* __restrict__ kk,
    const float* __restrict__ Wa,
    const float* __restrict__ ba,
    float* __restrict__ out)
{
    const int blk = blockIdx.x;          // grid = B * (L/ST) = 512
    const int b   = blk >> 6;            // / (L/ST)
    const int s0  = (blk & 63) * ST;
    const int tid = threadIdx.x;

    __shared__ float  a_sh[ST][L];       // 16 KB: alpha then softmax weights
    __shared__ float4 part[3][ST][64];   // 24 KB: cross-wave partials

    const float  ba0  = ba[0];
    const float* __restrict__ qrow = qb + (b * L + s0) * U;  // wave-uniform
    const float* __restrict__ kb   = kk + b * L * U;

    // ---- part A: alpha[s][t] = ba + sum_u tanh(q[s,u]+k[t,u])*Wa[u] ----
    #pragma unroll 1
    for (int i = 0; i < 2; ++i) {
        const int t = tid + i * 256;
        float kv[U];
        const float4* k4 = (const float4*)(kb + t * U);
        #pragma unroll
        for (int c = 0; c < 8; ++c) {
            float4 v = k4[c];
            kv[4 * c] = v.x; kv[4 * c + 1] = v.y; kv[4 * c + 2] = v.z; kv[4 * c + 3] = v.w;
        }
        #pragma unroll 1
        for (int s = 0; s < ST; ++s) {
            const float* __restrict__ q = qrow + s * U;   // uniform -> s_load
            float acc = ba0;
            #pragma unroll
            for (int u = 0; u < U; ++u)
                acc = fmaf(tanh_fast(q[u] + kv[u]), Wa[u], acc);
            a_sh[s][t] = acc;
        }
    }
    __syncthreads();

    // ---- part B: softmax over t per row; wave w handles rows 2w, 2w+1 ----
    {
        const int wv = tid >> 6, ln = tid & 63;
        #pragma unroll 1
        for (int s = wv * 2; s < wv * 2 + 2; ++s) {
            float v[8];
            #pragma unroll
            for (int j = 0; j < 8; ++j) v[j] = a_sh[s][ln + 64 * j];
            float m = v[0];
            #pragma unroll
            for (int j = 1; j < 8; ++j) m = fmaxf(m, v[j]);
            #pragma unroll
            for (int off = 1; off < 64; off <<= 1) m = fmaxf(m, __shfl_xor(m, off));
            float e[8], sum = 0.f;
            #pragma unroll
            for (int j = 0; j < 8; ++j) { e[j] = __expf(v[j] - m); sum += e[j]; }
            #pragma unroll
            for (int off = 1; off < 64; off <<= 1) sum += __shfl_xor(sum, off);
            float inv = 1.f / sum;
            #pragma unroll
            for (int j = 0; j < 8; ++j) a_sh[s][ln + 64 * j] = e[j] * inv;
        }
    }
    __syncthreads();

    // ---- part C: out[s][d] = sum_t a[s][t] * x[b,t,d] ----
    // wave tq owns t in [tq*128, tq*128+128); lane dg owns d-float4 dg
    const int tq = tid >> 6;
    const int dg = tid & 63;
    const float4* __restrict__ x4 = (const float4*)(x + b * L * D);

    float4 acc[ST];
    #pragma unroll
    for (int s = 0; s < ST; ++s) acc[s] = make_float4(0.f, 0.f, 0.f, 0.f);

    #pragma unroll 1
    for (int jj = 0; jj < 32; ++jj) {
        const int tj = tq * 32 + jj;             // float4-group of t
        float4 av[ST];
        #pragma unroll
        for (int s = 0; s < ST; ++s) av[s] = ((const float4*)a_sh[s])[tj];
        #pragma unroll
        for (int c = 0; c < 4; ++c) {
            const int t = 4 * tj + c;
            float4 xv = x4[t * 64 + dg];
            #pragma unroll
            for (int s = 0; s < ST; ++s) {
                float a = (c == 0) ? av[s].x : (c == 1) ? av[s].y : (c == 2) ? av[s].z : av[s].w;
                acc[s].x = fmaf(a, xv.x, acc[s].x);
                acc[s].y = fmaf(a, xv.y, acc[s].y);
                acc[s].z = fmaf(a, xv.z, acc[s].z);
                acc[s].w = fmaf(a, xv.w, acc[s].w);
            }
        }
    }

    if (tq > 0) {
        #pragma unroll
        for (int s = 0; s < ST; ++s) part[tq - 1][s][dg] = acc[s];
    }
    __syncthreads();
    if (tq == 0) {
        float4* __restrict__ out4 = (float4*)out;
        #pragma unroll
        for (int s = 0; s < ST; ++s) {
            float4 p0 = part[0][s][dg], p1 = part[1][s][dg], p2 = part[2][s][dg];
            float4 r = acc[s];
            r.x += p0.x + p1.x + p2.x;
            r.y += p0.y + p1.y + p2.y;
            r.z += p0.z + p1.z + p2.z;
            r.w += p0.w + p1.w + p2.w;
            out4[(b * L + s0 + s) * 64 + dg] = r;
        }
    }
}

extern "C" void kernel_launch(void* const* d_in, const int* in_sizes, int n_in,
                              void* d_out, int out_size, void* d_ws, size_t ws_size,
                              hipStream_t stream)
{
    const float* x  = (const float*)d_in[0];
    const float* Wt = (const float*)d_in[1];
    const float* Wx = (const float*)d_in[2];
    const float* bh = (const float*)d_in[3];
    const float* Wa = (const float*)d_in[4];
    const float* ba = (const float*)d_in[5];
    float* out = (float*)d_out;

    float* qb = (float*)d_ws;                    // B*L*U floats
    float* kk = qb + B * L * U;                  // B*L*U floats

    qk_kernel<<<B * L / TR, 256, 0, stream>>>(x, Wt, Wx, bh, qb, kk);
    attn_kernel<<<B * (L / ST), 256, 0, stream>>>(x, qb, kk, Wa, ba, out);
}

// Round 3
// 111.085 us; speedup vs baseline: 1.7744x; 1.0951x over previous
//
#include <hip/hip_runtime.h>

#define B 8
#define L 512
#define D 256
#define U 32
#define ST 8          // queries (s) per attn block
#define TR 8          // rows per qk block

// tanh(z) = 1 - 2/(exp(2z)+1), exp via hw exp2: 2*log2(e) = 2.885390082
__device__ __forceinline__ float tanh_fast(float z) {
    float e = __builtin_amdgcn_exp2f(z * 2.885390081777927f);
    return 1.f - 2.f * __builtin_amdgcn_rcpf(e + 1.f);
}

// ---------------------------------------------------------------------------
// qk: qb[row,u] = sum_d x[row,d]*Wt[d,u] + bh[u];  kk[row,u] = sum_d x*Wx
// grid = B*L/TR = 512 blocks, 256 threads = 8 rows x 32 u
// per d: wave reads one 128B line of Wt and one of Wx (broadcast across rows)
// ---------------------------------------------------------------------------
__global__ __launch_bounds__(256) void qk_kernel(
    const float* __restrict__ x,
    const float* __restrict__ Wt,
    const float* __restrict__ Wx,
    const float* __restrict__ bh,
    float* __restrict__ qb,
    float* __restrict__ kk)
{
    __shared__ float xs[TR][D + 1];
    const int row0 = blockIdx.x * TR;
    const int tid  = threadIdx.x;

    // stage x tile (TR*D = 2048 floats) via float4: 512 float4, 2 per thread
    const float4* xg = (const float4*)(x + row0 * D);
    #pragma unroll
    for (int i = tid; i < TR * D / 4; i += 256) {
        float4 v = xg[i];
        int r = i >> 6;              // / (D/4)
        int c = (i & 63) << 2;
        xs[r][c] = v.x; xs[r][c + 1] = v.y; xs[r][c + 2] = v.z; xs[r][c + 3] = v.w;
    }
    __syncthreads();

    const int r = tid >> 5;          // 0..7
    const int u = tid & 31;

    float qa = 0.f, ka = 0.f;
    #pragma unroll 8
    for (int d = 0; d < D; ++d) {
        float xv = xs[r][d];
        qa = fmaf(xv, Wt[d * U + u], qa);
        ka = fmaf(xv, Wx[d * U + u], ka);
    }
    const int row = row0 + r;
    qb[row * U + u] = qa + bh[u];
    kk[row * U + u] = ka;
}

// ---------------------------------------------------------------------------
// attn: one block per (b, s-tile of 8). 512 threads = 8 waves.
// ---------------------------------------------------------------------------
__global__ __launch_bounds__(512) void attn_kernel(
    const float* __restrict__ x,
    const float* __restrict__ qb,
    const float* __restrict__ kk,
    const float* __restrict__ Wa,
    const float* __restrict__ ba,
    float* __restrict__ out)
{
    const int blk = blockIdx.x;          // grid = B * (L/ST) = 512
    const int b   = blk >> 6;            // / (L/ST)
    const int s0  = (blk & 63) * ST;
    const int tid = threadIdx.x;

    __shared__ float  a_sh[ST][L];       // 16 KB: alpha, then softmax weights
    __shared__ float4 part[7][ST][64];   // 56 KB: cross-wave partials

    const float  ba0  = ba[0];
    const float* __restrict__ qrow = qb + (b * L + s0) * U;  // wave-uniform
    const float* __restrict__ kb   = kk + b * L * U;

    // ---- part A: alpha[s][t] = ba + sum_u tanh(q[s,u]+k[t,u])*Wa[u] ----
    {
        const int t = tid;               // 512 threads cover all t
        float kv[U];
        const float4* k4 = (const float4*)(kb + t * U);
        #pragma unroll
        for (int c = 0; c < 8; ++c) {
            float4 v = k4[c];
            kv[4 * c] = v.x; kv[4 * c + 1] = v.y; kv[4 * c + 2] = v.z; kv[4 * c + 3] = v.w;
        }
        #pragma unroll 1
        for (int s = 0; s < ST; ++s) {
            const float* __restrict__ q = qrow + s * U;   // uniform -> s_load
            float acc = ba0;
            #pragma unroll
            for (int u = 0; u < U; ++u)
                acc = fmaf(tanh_fast(q[u] + kv[u]), Wa[u], acc);
            a_sh[s][t] = acc;
        }
    }
    __syncthreads();

    // ---- part B: softmax over t; wave w handles row w ----
    {
        const int s = tid >> 6, ln = tid & 63;
        float v[8];
        #pragma unroll
        for (int j = 0; j < 8; ++j) v[j] = a_sh[s][ln + 64 * j];
        float m = v[0];
        #pragma unroll
        for (int j = 1; j < 8; ++j) m = fmaxf(m, v[j]);
        #pragma unroll
        for (int off = 1; off < 64; off <<= 1) m = fmaxf(m, __shfl_xor(m, off));
        float e[8], sum = 0.f;
        #pragma unroll
        for (int j = 0; j < 8; ++j) { e[j] = __expf(v[j] - m); sum += e[j]; }
        #pragma unroll
        for (int off = 1; off < 64; off <<= 1) sum += __shfl_xor(sum, off);
        float inv = 1.f / sum;
        #pragma unroll
        for (int j = 0; j < 8; ++j) a_sh[s][ln + 64 * j] = e[j] * inv;
    }
    __syncthreads();

    // ---- part C: out[s][d] = sum_t a[s][t] * x[b,t,d] ----
    // wave tq owns t in [tq*64, tq*64+64); lane dg owns d-float4 dg
    const int tq = tid >> 6;             // 0..7
    const int dg = tid & 63;
    const float4* __restrict__ x4 = (const float4*)(x + b * L * D);

    float4 acc[ST];
    #pragma unroll
    for (int s = 0; s < ST; ++s) acc[s] = make_float4(0.f, 0.f, 0.f, 0.f);

    #pragma unroll 2
    for (int jj = 0; jj < 16; ++jj) {
        const int tj = tq * 16 + jj;             // float4-group of t
        float4 av[ST];
        #pragma unroll
        for (int s = 0; s < ST; ++s) av[s] = ((const float4*)a_sh[s])[tj];
        #pragma unroll
        for (int c = 0; c < 4; ++c) {
            const int t = 4 * tj + c;
            float4 xv = x4[t * 64 + dg];
            #pragma unroll
            for (int s = 0; s < ST; ++s) {
                float a = (c == 0) ? av[s].x : (c == 1) ? av[s].y : (c == 2) ? av[s].z : av[s].w;
                acc[s].x = fmaf(a, xv.x, acc[s].x);
                acc[s].y = fmaf(a, xv.y, acc[s].y);
                acc[s].z = fmaf(a, xv.z, acc[s].z);
                acc[s].w = fmaf(a, xv.w, acc[s].w);
            }
        }
    }

    if (tq > 0) {
        #pragma unroll
        for (int s = 0; s < ST; ++s) part[tq - 1][s][dg] = acc[s];
    }
    __syncthreads();
    if (tq == 0) {
        float4* __restrict__ out4 = (float4*)out;
        #pragma unroll
        for (int s = 0; s < ST; ++s) {
            float4 r = acc[s];
            #pragma unroll
            for (int w = 0; w < 7; ++w) {
                float4 p = part[w][s][dg];
                r.x += p.x; r.y += p.y; r.z += p.z; r.w += p.w;
            }
            out4[(b * L + s0 + s) * 64 + dg] = r;
        }
    }
}

extern "C" void kernel_launch(void* const* d_in, const int* in_sizes, int n_in,
                              void* d_out, int out_size, void* d_ws, size_t ws_size,
                              hipStream_t stream)
{
    const float* x  = (const float*)d_in[0];
    const float* Wt = (const float*)d_in[1];
    const float* Wx = (const float*)d_in[2];
    const float* bh = (const float*)d_in[3];
    const float* Wa = (const float*)d_in[4];
    const float* ba = (const float*)d_in[5];
    float* out = (float*)d_out;

    float* qb = (float*)d_ws;                    // B*L*U floats
    float* kk = qb + B * L * U;                  // B*L*U floats

    qk_kernel<<<B * L / TR, 256, 0, stream>>>(x, Wt, Wx, bh, qb, kk);
    attn_kernel<<<B * (L / ST), 512, 0, stream>>>(x, qb, kk, Wa, ba, out);
}